// Round 8
// baseline (36.235 us; speedup 1.0000x reference)
//
#include <hip/hip_runtime.h>
#include <math.h>

#define HALF_PI   1.57079632679489662f
#define INV_SQRT2 0.70710678118654752f
#define NPART     1024   // edge-kernel blocks; covers E <= 1024*256*4 = 1048576

// ---------------------------------------------------------------------------
// K1: node projections. One node per wave per iteration, grid-stride.
// Lane l holds feat[n][4l..4l+3]; weight fragments (8 rows x 4 dims = 32
// VGPRs) preloaded once. Multi-value butterfly reduce: 10 shuffles/node.
// ---------------------------------------------------------------------------
__global__ __launch_bounds__(256) void node_qk(
        const float* __restrict__ feat,
        const float* __restrict__ Wq, const float* __restrict__ bq,
        const float* __restrict__ Wk, const float* __restrict__ bk,
        float* __restrict__ qtab, float* __restrict__ ktab, int N) {
    const int lane  = threadIdx.x & 63;
    const int wid   = (int)((blockIdx.x * blockDim.x + threadIdx.x) >> 6);
    const int nwid  = (int)((gridDim.x * blockDim.x) >> 6);

    float4 wq4[4], wk4[4];
    #pragma unroll
    for (int q = 0; q < 4; ++q) {
        wq4[q] = reinterpret_cast<const float4*>(Wq + q * 256)[lane];
        wk4[q] = reinterpret_cast<const float4*>(Wk + q * 256)[lane];
    }
    const int  g    = lane >> 3;
    const float bias = (g < 4) ? bq[g] : bk[g & 3];
    const bool hi  = (lane & 32) != 0;
    const bool s16 = (lane & 16) != 0;
    const bool s8  = (lane & 8)  != 0;

    for (int n = wid; n < N; n += nwid) {
        float4 f = reinterpret_cast<const float4*>(feat)[(size_t)n * 64 + lane];
        float acc[8];
        #pragma unroll
        for (int q = 0; q < 4; ++q) {
            acc[q]     = f.x * wq4[q].x + f.y * wq4[q].y + f.z * wq4[q].z + f.w * wq4[q].w;
            acc[4 + q] = f.x * wk4[q].x + f.y * wk4[q].y + f.z * wk4[q].z + f.w * wk4[q].w;
        }
        // multi-value butterfly: 10 shuffles per node
        #pragma unroll
        for (int j = 0; j < 4; ++j) {
            float give = hi ? acc[j] : acc[j + 4];
            float r = __shfl_xor(give, 32, 64);
            acc[j]     += hi ? 0.f : r;
            acc[j + 4] += hi ? r : 0.f;
        }
        #pragma unroll
        for (int j = 0; j < 2; ++j) {
            float giveLow  = hi ? acc[6 + j] : acc[2 + j];
            float giveHigh = hi ? acc[4 + j] : acc[j];
            float give = s16 ? giveHigh : giveLow;
            float r = __shfl_xor(give, 16, 64);
            acc[j]     += (!hi && !s16) ? r : 0.f;
            acc[2 + j] += (!hi &&  s16) ? r : 0.f;
            acc[4 + j] += ( hi && !s16) ? r : 0.f;
            acc[6 + j] += ( hi &&  s16) ? r : 0.f;
        }
        float a_even = hi ? (s16 ? acc[6] : acc[4]) : (s16 ? acc[2] : acc[0]);
        float a_odd  = hi ? (s16 ? acc[7] : acc[5]) : (s16 ? acc[3] : acc[1]);
        float give3 = s8 ? a_even : a_odd;
        float r3 = __shfl_xor(give3, 8, 64);
        float v = (s8 ? a_odd : a_even) + r3;
        v += __shfl_xor(v, 4, 64);
        v += __shfl_xor(v, 2, 64);
        v += __shfl_xor(v, 1, 64);
        if ((lane & 7) == 0) {
            float t = tanhf(v + bias) * HALF_PI;
            if (g < 4) qtab[(size_t)n * 4 + g] = t;
            else       ktab[(size_t)n * 4 + (g & 3)] = t;
        }
    }
}

// 4-qubit real circuit for one edge: returns exp(attn/4)
__device__ __forceinline__ float edge_ex(float4 qv, float4 kv,
                                         const float* scz, const float* scx) {
    float qa[4] = {qv.x, qv.y, qv.z, qv.w};
    float ka[4] = {kv.x, kv.y, kv.z, kv.w};
    float u[4][2];
    #pragma unroll
    for (int w = 0; w < 4; ++w) {
        float s, c;
        __sincosf(qa[w] * 0.5f, &s, &c);
        u[w][0] = (c + s) * INV_SQRT2;
        u[w][1] = (c - s) * INV_SQRT2;
    }
    float a[16];
    #pragma unroll
    for (int x = 0; x < 16; ++x)
        a[x] = u[0][(x >> 3) & 1] * u[1][(x >> 2) & 1] *
               u[2][(x >> 1) & 1] * u[3][x & 1];
    #pragma unroll
    for (int w = 0; w < 4; ++w) {
        float si, co;
        __sincosf(ka[w] * 0.5f, &si, &co);
        const int cb = 1 << (3 - w);
        const int tb = 1 << (3 - ((w + 1) & 3));
        #pragma unroll
        for (int x = 0; x < 16; ++x) {
            if ((x & cb) && !(x & tb)) {
                float a0 = a[x], a1 = a[x | tb];
                a[x]      = co * a0 - si * a1;
                a[x | tb] = si * a0 + co * a1;
            }
        }
    }
    float attn = 0.f;
    #pragma unroll
    for (int q = 0; q < 4; ++q) {
        const int bit = 1 << (3 - q);
        float sz = 0.f, sx = 0.f;
        #pragma unroll
        for (int x = 0; x < 16; ++x) {
            float pp = a[x] * a[x];
            sz += (x & bit) ? -pp : pp;
            if (!(x & bit)) sx += a[x] * a[x | bit];
        }
        attn += scz[q] * sz - scx[q] * (2.f * sx);
    }
    return __expf(attn * 0.25f);
}

// ---------------------------------------------------------------------------
// K2: per-edge circuit, 4 CONTIGUOUS edges per thread. Index rows loaded as
// int4 (one 16B transaction per row); 8 independent table gathers in flight
// per thread; tables (1.6 MB total) are L2-resident. Deterministic per-block
// partial sums (block b owns contiguous edges [b*1024, b*1024+1024)).
// ---------------------------------------------------------------------------
__global__ __launch_bounds__(256) void edge_attn(
        const int* __restrict__ ei,
        const float4* __restrict__ qtab, const float4* __restrict__ ktab,
        const float* __restrict__ qp,
        float* __restrict__ out, float* __restrict__ partial, int E) {
    __shared__ float scz[4], scx[4];
    __shared__ float red[256];
    const int tid = threadIdx.x;
    if (tid < 4) {
        float phi = qp[3 * tid + 0];
        float th  = qp[3 * tid + 1];
        float sth, cth;
        sincosf(th, &sth, &cth);
        scz[tid] = cth;
        scx[tid] = sth * cosf(phi);
    }
    __syncthreads();

    const int base = (blockIdx.x * 256 + tid) * 4;
    float lsum = 0.f;

    if (base + 3 < E && ((E & 3) == 0)) {
        // fast path: one int4 per index row, 8 gathers issued back-to-back
        int4 sv = *reinterpret_cast<const int4*>(ei + base);
        int4 dv = *reinterpret_cast<const int4*>(ei + E + base);
        float4 q0 = qtab[sv.x], q1 = qtab[sv.y], q2 = qtab[sv.z], q3 = qtab[sv.w];
        float4 k0 = ktab[dv.x], k1 = ktab[dv.y], k2 = ktab[dv.z], k3 = ktab[dv.w];
        float e0 = edge_ex(q0, k0, scz, scx);
        float e1 = edge_ex(q1, k1, scz, scx);
        float e2 = edge_ex(q2, k2, scz, scx);
        float e3 = edge_ex(q3, k3, scz, scx);
        *reinterpret_cast<float4*>(out + base) = make_float4(e0, e1, e2, e3);
        lsum = (e0 + e1) + (e2 + e3);
    } else if (base < E) {
        #pragma unroll
        for (int j = 0; j < 4; ++j) {
            const int e = base + j;
            if (e < E) {
                float v = edge_ex(qtab[ei[e]], ktab[ei[E + e]], scz, scx);
                out[e] = v;
                lsum += v;
            }
        }
    }

    red[tid] = lsum;
    __syncthreads();
    #pragma unroll
    for (int s = 128; s > 0; s >>= 1) {
        if (tid < s) red[tid] += red[tid + s];
        __syncthreads();
    }
    if (tid == 0) partial[blockIdx.x] = red[0];
}

// ---------------------------------------------------------------------------
// K3: every block redundantly tree-reduces the NPART partials in identical
// order (same float in all blocks), then normalizes its float4 slice.
// ---------------------------------------------------------------------------
__global__ __launch_bounds__(256) void normalize_out(
        float* __restrict__ out, const float* __restrict__ partial, int E) {
    __shared__ float red[256];
    const int tid = threadIdx.x;
    float s = 0.f;
    #pragma unroll
    for (int k = 0; k < NPART / 256; ++k) s += partial[tid + k * 256];
    red[tid] = s;
    __syncthreads();
    #pragma unroll
    for (int st = 128; st > 0; st >>= 1) {
        if (tid < st) red[tid] += red[tid + st];
        __syncthreads();
    }
    const float inv = 1.f / red[0];

    const int nv4    = E >> 2;                       // full float4 groups
    const int stride = (int)(gridDim.x * 256);
    float4* out4 = reinterpret_cast<float4*>(out);
    for (int i = blockIdx.x * 256 + tid; i < nv4; i += stride) {
        float4 v = out4[i];
        v.x *= inv; v.y *= inv; v.z *= inv; v.w *= inv;
        out4[i] = v;
    }
    // tail (E not multiple of 4)
    const int tail = nv4 << 2;
    for (int e = tail + blockIdx.x * 256 + tid; e < E; e += stride)
        out[e] *= inv;
}

extern "C" void kernel_launch(void* const* d_in, const int* in_sizes, int n_in,
                              void* d_out, int out_size, void* d_ws, size_t ws_size,
                              hipStream_t stream) {
    const float* feat = (const float*)d_in[0];
    const int*   ei   = (const int*)d_in[1];
    const float* Wq   = (const float*)d_in[2];
    const float* bq   = (const float*)d_in[3];
    const float* Wk   = (const float*)d_in[4];
    const float* bk   = (const float*)d_in[5];
    const float* qp   = (const float*)d_in[6];

    int D = in_sizes[2] / 4;          // 256
    int N = in_sizes[0] / D;          // 50000
    int E = in_sizes[1] / 2;          // 800000
    (void)D;

    float* ws      = (float*)d_ws;
    float* partial = ws;                         // NPART floats (4 KB)
    float* qtab    = ws + NPART;                 // 4N floats (16B aligned)
    float* ktab    = qtab + (size_t)N * 4;       // 4N floats
    float* out     = (float*)d_out;

    node_qk<<<2048, 256, 0, stream>>>(feat, Wq, bq, Wk, bk, qtab, ktab, N);
    edge_attn<<<NPART, 256, 0, stream>>>(ei, (const float4*)qtab, (const float4*)ktab,
                                         qp, out, partial, E);
    normalize_out<<<1024, 256, 0, stream>>>(out, partial, E);
}